// Round 10
// baseline (512.726 us; speedup 1.0000x reference)
//
#include <hip/hip_runtime.h>

#define T_SEQ 2048
#define C_DIM 1024
#define NH    16
#define NKV   4
#define HD    64
#define WIN   512
#define NBLK  768u

typedef __bf16 bf16x8 __attribute__((ext_vector_type(8)));
typedef __bf16 bf16x4 __attribute__((ext_vector_type(4)));
typedef float f32x4 __attribute__((ext_vector_type(4)));

#define MFMA16(a, b, c) __builtin_amdgcn_mfma_f32_16x16x32_bf16(a, b, c, 0, 0, 0)

// async global->LDS, 16B per lane, dest = wave-uniform base + lane*16
#define GLD16(g, s)                                                          \
  __builtin_amdgcn_global_load_lds(                                          \
      (const __attribute__((address_space(1))) void*)(g),                    \
      (__attribute__((address_space(3))) void*)(s), 16, 0, 0)

// ---------------- software grid barrier (persistent-kernel pattern) -------------------
// All 768 blocks are co-resident by construction (LDS 41984B -> exactly 3/CU; grid =
// 256 CU x 3; LB(256,3) caps VGPR), so a spin barrier cannot starve. Device-scope
// (agent) atomics work cross-XCD (m20); __syncthreads drains each wave's stores to
// its XCD L2, thread0's __threadfence (agent release) writes back before arrival;
// acquire on the spin/last-arrival + trailing fence invalidates stale lines (G16).
// Generation counter makes the pair reusable; bailout turns a logic bug into a wrong
// answer instead of a hang.
__device__ __forceinline__ void grid_bar(unsigned* bar) {
  __syncthreads();
  if (threadIdx.x == 0) {
    __threadfence();
    unsigned g = __hip_atomic_load(bar + 1, __ATOMIC_ACQUIRE, __HIP_MEMORY_SCOPE_AGENT);
    unsigned a = __hip_atomic_fetch_add(bar, 1u, __ATOMIC_ACQ_REL, __HIP_MEMORY_SCOPE_AGENT);
    if (a == NBLK - 1u) {
      __hip_atomic_store(bar, 0u, __ATOMIC_RELAXED, __HIP_MEMORY_SCOPE_AGENT);
      __hip_atomic_fetch_add(bar + 1, 1u, __ATOMIC_ACQ_REL, __HIP_MEMORY_SCOPE_AGENT);
    } else {
      for (unsigned spin = 0; spin < (1u << 23); ++spin) {
        if (__hip_atomic_load(bar + 1, __ATOMIC_ACQUIRE, __HIP_MEMORY_SCOPE_AGENT) != g)
          break;
        __builtin_amdgcn_s_sleep(2);
      }
    }
    __threadfence();
  }
  __syncthreads();
}

// ---------------- phase 0: fused f32->bf16 casts + RoPE table (R7, proven) -------------
__device__ __forceinline__ void prep_body(int b, int tid,
                                          const float* __restrict__ x,
                                          const float* __restrict__ Wq,
                                          const float* __restrict__ Wkv,
                                          const float* __restrict__ Wp,
                                          __bf16* __restrict__ xb,
                                          __bf16* __restrict__ Wqkvb,
                                          __bf16* __restrict__ Wpb,
                                          float2* __restrict__ ropeT) {
  if (b >= 4608) {
    int idx = (b - 4608) * 256 + tid;  // < 65536
    int t = idx >> 5, i = idx & 31;
    float theta = exp2f(-(float)i * (13.287712379549449f / 32.0f));
    float s, c;
    sincosf((float)t * theta, &s, &c);
    ropeT[idx] = make_float2(c, s);
    return;
  }
  const float* src;
  __bf16* dst;
  int off;
  if (b < 2048)      { src = x;   dst = xb;                off = b; }
  else if (b < 3072) { src = Wq;  dst = Wqkvb;             off = b - 2048; }
  else if (b < 3584) { src = Wkv; dst = Wqkvb + (1 << 20); off = b - 3072; }
  else               { src = Wp;  dst = Wpb;               off = b - 3584; }
  int i = off * 1024 + tid * 4;
  float4 v = *(const float4*)(src + i);
  bf16x4 o;
  o[0] = (__bf16)v.x; o[1] = (__bf16)v.y; o[2] = (__bf16)v.z; o[3] = (__bf16)v.w;
  *(bf16x4*)(dst + i) = o;
}

// ---------------- GEMM core: R4-proven (106.4us). 64x64 tile, BK=64, 16x16x32 MFMA,
// global_load_lds staging + LDS dbuf, source-side XOR swizzle (m173). ----------------
__device__ __forceinline__ void gemm_core64(const __bf16* __restrict__ A,
                                            const __bf16* __restrict__ B,
                                            int K,
                                            __bf16* AsB, __bf16* BsB,
                                            f32x4 (&acc)[4]) {
  const int tid = threadIdx.x;
  const int w = tid >> 6, l = tid & 63;
  const int quad = l >> 4, r16 = l & 15;
  const int srow = w * 16 + (l >> 3);
  const size_t soff = (size_t)srow * K + (size_t)(((l & 7) ^ (l >> 3)) * 8);
  const __bf16* gA = A + soff;
  const __bf16* gB = B + soff;
  __bf16* const lA = AsB + w * 1024;
  __bf16* const lB = BsB + w * 1024;
  const size_t rstep = (size_t)8 * K;
  int rA[2], rB[4][2];
#pragma unroll
  for (int ks = 0; ks < 2; ++ks) {
    int row = w * 16 + r16;
    rA[ks] = row * 64 + (((ks * 4 + quad) ^ (row & 7)) * 8);
  }
#pragma unroll
  for (int nt = 0; nt < 4; ++nt)
#pragma unroll
    for (int ks = 0; ks < 2; ++ks) {
      int row = nt * 16 + r16;
      rB[nt][ks] = row * 64 + (((ks * 4 + quad) ^ (row & 7)) * 8);
    }
  const int nIter = K >> 6;
  GLD16(gA, lA);
  GLD16(gA + rstep, lA + 512);
  GLD16(gB, lB);
  GLD16(gB + rstep, lB + 512);
  __syncthreads();
  int cur = 0;
  for (int it = 0; it < nIter; ++it) {
    if (it + 1 < nIter) {  // async-stage next K-slab into the other buffer
      const __bf16* ga = gA + ((it + 1) << 6);
      const __bf16* gb = gB + ((it + 1) << 6);
      __bf16* la = lA + ((cur ^ 1) << 12);
      __bf16* lb = lB + ((cur ^ 1) << 12);
      GLD16(ga, la);
      GLD16(ga + rstep, la + 512);
      GLD16(gb, lb);
      GLD16(gb + rstep, lb + 512);
    }
    const __bf16* Asc = AsB + (cur << 12);
    const __bf16* Bsc = BsB + (cur << 12);
#pragma unroll
    for (int ks = 0; ks < 2; ++ks) {
      bf16x8 fa  = *(const bf16x8*)(Asc + rA[ks]);
      bf16x8 fb0 = *(const bf16x8*)(Bsc + rB[0][ks]);
      bf16x8 fb1 = *(const bf16x8*)(Bsc + rB[1][ks]);
      bf16x8 fb2 = *(const bf16x8*)(Bsc + rB[2][ks]);
      bf16x8 fb3 = *(const bf16x8*)(Bsc + rB[3][ks]);
      acc[0] = MFMA16(fa, fb0, acc[0]);
      acc[1] = MFMA16(fa, fb1, acc[1]);
      acc[2] = MFMA16(fa, fb2, acc[2]);
      acc[3] = MFMA16(fa, fb3, acc[3]);
    }
    if (it + 1 < nIter) {
      __syncthreads();  // drains vmcnt(0): next slab resident; old buffer free
      cur ^= 1;
    }
  }
  __syncthreads();  // staging buffers reusable by caller after this
}

// ---------------- phase 1: QKV GEMM + fused norm+RoPE (Q,K) / V-transpose -------------
__device__ __forceinline__ void qkv_body(int bx, int by, __bf16* smem,
                                         const __bf16* __restrict__ xb,
                                         const __bf16* __restrict__ Wqkvb,
                                         const float2* __restrict__ ropeT,
                                         __bf16* __restrict__ Qb,
                                         __bf16* __restrict__ Kb,
                                         __bf16* __restrict__ Vt) {
  __bf16* AsB = smem;
  __bf16* BsB = smem + 8192;
  f32x4 acc[4] = {};
  const int m0 = by * 64, n0 = bx * 64;
  gemm_core64(xb + (size_t)m0 * C_DIM, Wqkvb + (size_t)n0 * C_DIM, C_DIM, AsB, BsB, acc);
  const int tid = threadIdx.x;
  const int w = tid >> 6, l = tid & 63, quad = l >> 4, r16 = l & 15;
  if (n0 < 1280) {  // Q or K: L2-norm + RoPE
    const bool isQ = n0 < 1024;
    const int head = isQ ? (n0 >> 6) : ((n0 - 1024) >> 6);
    __bf16* dstBase = (isQ ? Qb : Kb) + (size_t)head * T_SEQ * HD;
    const float osc = isQ ? 0.125f : 1.0f;  // fold 1/sqrt(d) into Q (2^-3 exact)
#pragma unroll
    for (int r = 0; r < 4; ++r) {
      float ss = acc[0][r] * acc[0][r] + acc[1][r] * acc[1][r] +
                 acc[2][r] * acc[2][r] + acc[3][r] * acc[3][r];
#pragma unroll
      for (int m = 1; m < 16; m <<= 1) ss += __shfl_xor(ss, m, 64);
      const float inv = osc / (sqrtf(ss) + 1e-6f);
      const int t = m0 + w * 16 + quad * 4 + r;
      const float2 cs0 = ropeT[t * 32 + r16];
      const float2 cs1 = ropeT[t * 32 + 16 + r16];
      const float v0 = acc[0][r] * inv, v1 = acc[1][r] * inv;
      const float v2 = acc[2][r] * inv, v3 = acc[3][r] * inv;
      __bf16* dst = dstBase + (size_t)t * HD;
      dst[r16]      = (__bf16)(v0 * cs0.x - v2 * cs0.y);
      dst[16 + r16] = (__bf16)(v1 * cs1.x - v3 * cs1.y);
      dst[32 + r16] = (__bf16)(v2 * cs0.x + v0 * cs0.y);
      dst[48 + r16] = (__bf16)(v3 * cs1.x + v1 * cs1.y);
    }
  } else {  // V: transpose to Vt[kvh][d][t] via reused LDS
    const int kvh = (n0 - 1280) >> 6;
    __bf16* Vs = smem;  // [64 d][stride 136] = 17.4 KB
#pragma unroll
    for (int nt = 0; nt < 4; ++nt)
#pragma unroll
      for (int r = 0; r < 4; ++r)
        Vs[(nt * 16 + r16) * 136 + w * 16 + quad * 4 + r] = (__bf16)acc[nt][r];
    __syncthreads();
    const int d = tid >> 2, tc = (tid & 3) * 16;
    __bf16* dst = Vt + ((size_t)kvh * HD + d) * T_SEQ + m0 + tc;
    bf16x8 v0 = *(const bf16x8*)(Vs + d * 136 + tc);
    bf16x8 v1 = *(const bf16x8*)(Vs + d * 136 + tc + 8);
    *(bf16x8*)dst = v0;
    *(bf16x8*)(dst + 8) = v1;
  }
}

// ---------------- phase 2: MFMA sliding-window attention (R12-proven) -----------------
__device__ __forceinline__ void attn_body(int bx, int h, __bf16* smem,
                                          const __bf16* __restrict__ Qb,
                                          const __bf16* __restrict__ Kb,
                                          const __bf16* __restrict__ Vt,
                                          __bf16* __restrict__ Yb) {
  __bf16* KVs0 = smem;          // [2][8192]: per buf K[64][64] | V[64][64]
  __bf16* Pl   = smem + 16384;  // [4][16][72] = 4608 elems
  const int kvh = h >> 2;
  const int t0 = bx * 64;
  const int tid = threadIdx.x;
  const int w = tid >> 6, l = tid & 63;
  const int quad = l >> 4, r16 = l & 15;
  const int rr = l >> 3;          // 0..7: staging row within 8-row group
  const int cc = (l & 7) ^ rr;    // swizzled source chunk
  const __bf16* qptr = Qb + ((size_t)h * T_SEQ + t0 + w * 16 + r16) * HD + quad * 8;
  bf16x8 aq0 = *(const bf16x8*)(qptr);
  bf16x8 aq1 = *(const bf16x8*)(qptr + 32);
  const int keyStart = max(0, t0 - (WIN - 1)) & ~63;
  const int nch = ((t0 + 64) - keyStart) >> 6;         // <= 9, block-uniform
  const __bf16* kbase = Kb + (size_t)kvh * T_SEQ * HD;
  const __bf16* vbase = Vt + (size_t)kvh * HD * T_SEQ;
  const int tq = t0 + w * 16 + quad * 4;  // + r
  f32x4 oacc[4] = {};
  float lsum[4] = {0.f, 0.f, 0.f, 0.f};

  {  // prologue: stage chunk 0 into buf 0
    __bf16* kd = KVs0 + w * 1024;
    __bf16* vd = KVs0 + 4096 + w * 1024;
    const __bf16* kg = kbase + (size_t)(keyStart + w * 16 + rr) * HD + cc * 8;
    const __bf16* vg = vbase + (size_t)(w * 16 + rr) * T_SEQ + keyStart + cc * 8;
    GLD16(kg, kd); GLD16(kg + 8 * HD, kd + 512);
    GLD16(vg, vd); GLD16(vg + 8 * T_SEQ, vd + 512);
  }
  __syncthreads();
  int buf = 0;
  for (int it = 0; it < nch; ++it) {
    const int key0 = keyStart + (it << 6);
    if (it + 1 < nch) {  // async-stage next chunk into the other buffer
      const int kn = key0 + 64;
      __bf16* kd = KVs0 + (buf ^ 1) * 8192 + w * 1024;
      __bf16* vd = KVs0 + (buf ^ 1) * 8192 + 4096 + w * 1024;
      const __bf16* kg = kbase + (size_t)(kn + w * 16 + rr) * HD + cc * 8;
      const __bf16* vg = vbase + (size_t)(w * 16 + rr) * T_SEQ + kn + cc * 8;
      GLD16(kg, kd); GLD16(kg + 8 * HD, kd + 512);
      GLD16(vg, vd); GLD16(vg + 8 * T_SEQ, vd + 512);
    }
    const __bf16* Ksc = KVs0 + buf * 8192;
    const __bf16* Vsc = Ksc + 4096;
    f32x4 s[4] = {};
#pragma unroll
    for (int nt = 0; nt < 4; ++nt) {
      const int row = nt * 16 + r16;
      bf16x8 bk0 = *(const bf16x8*)(Ksc + row * 64 + ((quad ^ (row & 7)) * 8));
      bf16x8 bk1 = *(const bf16x8*)(Ksc + row * 64 + (((4 + quad) ^ (row & 7)) * 8));
      s[nt] = MFMA16(aq0, bk0, s[nt]);
      s[nt] = MFMA16(aq1, bk1, s[nt]);
    }
#pragma unroll
    for (int nt = 0; nt < 4; ++nt) {
      const int key = key0 + nt * 16 + r16;
#pragma unroll
      for (int r = 0; r < 4; ++r) {
        bool valid = (key <= tq + r) && (key > tq + r - WIN);
        float p = valid ? __expf(s[nt][r]) : 0.0f;
        lsum[r] += p;
        Pl[w * 1152 + (quad * 4 + r) * 72 + nt * 16 + r16] = (__bf16)p;
      }
    }
    bf16x8 ap0 = *(const bf16x8*)(Pl + w * 1152 + r16 * 72 + quad * 8);
    bf16x8 ap1 = *(const bf16x8*)(Pl + w * 1152 + r16 * 72 + 32 + quad * 8);
#pragma unroll
    for (int nt = 0; nt < 4; ++nt) {
      const int d = nt * 16 + r16;
      bf16x8 bv0 = *(const bf16x8*)(Vsc + d * 64 + ((quad ^ (d & 7)) * 8));
      bf16x8 bv1 = *(const bf16x8*)(Vsc + d * 64 + (((4 + quad) ^ (d & 7)) * 8));
      oacc[nt] = MFMA16(ap0, bv0, oacc[nt]);
      oacc[nt] = MFMA16(ap1, bv1, oacc[nt]);
    }
    __syncthreads();  // drains vmcnt: next chunk resident; old buffer free
    buf ^= 1;
  }
#pragma unroll
  for (int r = 0; r < 4; ++r) {
#pragma unroll
    for (int m = 1; m < 16; m <<= 1) lsum[r] += __shfl_xor(lsum[r], m, 64);
  }
#pragma unroll
  for (int r = 0; r < 4; ++r) {
    const float inv = 1.0f / lsum[r];
    const size_t row = (size_t)(tq + r);
#pragma unroll
    for (int nt = 0; nt < 4; ++nt)
      Yb[row * C_DIM + h * HD + nt * 16 + r16] = (__bf16)(oacc[nt][r] * inv);
  }
}

// ---------------- phase 3: proj GEMM, f32 epilogue -----------------------------------
__device__ __forceinline__ void proj_body(int bx, int by, __bf16* smem,
                                          const __bf16* __restrict__ Yb,
                                          const __bf16* __restrict__ Wpb,
                                          float* __restrict__ C) {
  __bf16* AsB = smem;
  __bf16* BsB = smem + 8192;
  f32x4 acc[4] = {};
  const int m0 = by * 64, n0 = bx * 64;
  gemm_core64(Yb + (size_t)m0 * C_DIM, Wpb + (size_t)n0 * C_DIM, C_DIM, AsB, BsB, acc);
  const int tid = threadIdx.x;
  const int w = tid >> 6, l = tid & 63, quad = l >> 4, r16 = l & 15;
  const int mrow = m0 + w * 16 + quad * 4;
  const int ncol = n0 + r16;
#pragma unroll
  for (int r = 0; r < 4; ++r) {
    size_t rowoff = (size_t)(mrow + r) * C_DIM;
    C[rowoff + ncol]      = acc[0][r];
    C[rowoff + ncol + 16] = acc[1][r];
    C[rowoff + ncol + 32] = acc[2][r];
    C[rowoff + ncol + 48] = acc[3][r];
  }
}

// ---------------- fused persistent kernel, software grid barrier ----------------------
// R16: R8's cooperative launch produced all-zero output (launch-path failure); same
// fusion re-done as a NORMAL launch + software generation-barrier. Grid 768 x 256 =
// exactly 3 blocks/CU co-resident (LDS 41984B, LB(256,3)) -> spin barrier is safe.
// Phase bodies byte-identical to R4 (106.4us proven).
__global__ __launch_bounds__(256, 3) void fused_kernel(const float* __restrict__ x,
                                                       const float* __restrict__ Wq,
                                                       const float* __restrict__ Wkv,
                                                       const float* __restrict__ Wp,
                                                       float* __restrict__ out,
                                                       __bf16* __restrict__ xb,
                                                       __bf16* __restrict__ Wqkvb,
                                                       __bf16* __restrict__ Wpb,
                                                       __bf16* __restrict__ Qb,
                                                       __bf16* __restrict__ Kb,
                                                       __bf16* __restrict__ Vt,
                                                       __bf16* __restrict__ Yb,
                                                       float2* __restrict__ ropeT,
                                                       unsigned* __restrict__ bar) {
  __shared__ __align__(16) __bf16 smem[20992];  // 41984 B: gemm 32KB | attn KVs+Pl
  const int b = blockIdx.x;
  const int tid = threadIdx.x;

  // phase 0: prep (4864 virtual blocks, grid-stride)
  for (int vb = b; vb < 4864; vb += NBLK)
    prep_body(vb, tid, x, Wq, Wkv, Wp, xb, Wqkvb, Wpb, ropeT);
  grid_bar(bar);

  // phase 1: qkv (768 tiles, 1:1)
  qkv_body(b % 24, b / 24, smem, xb, Wqkvb, ropeT, Qb, Kb, Vt);
  grid_bar(bar);

  // phase 2: attention (512 tiles)
  if (b < 512) attn_body(b & 31, b >> 5, smem, Qb, Kb, Vt, Yb);
  grid_bar(bar);

  // phase 3: proj (512 tiles)
  if (b < 512) proj_body(b & 15, b >> 4, smem, Yb, Wpb, out);
}

extern "C" void kernel_launch(void* const* d_in, const int* in_sizes, int n_in,
                              void* d_out, int out_size, void* d_ws, size_t ws_size,
                              hipStream_t stream) {
  const float* x     = (const float*)d_in[0];
  const float* Wq    = (const float*)d_in[1];
  const float* Wkv   = (const float*)d_in[2];
  const float* Wproj = (const float*)d_in[3];
  float* out = (float*)d_out;

  __bf16* xb    = (__bf16*)d_ws;                         // [2048][1024]
  __bf16* Wqkvb = xb + (size_t)T_SEQ * C_DIM;            // [1536][1024]
  __bf16* Wpb   = Wqkvb + (size_t)1536 * C_DIM;          // [1024][1024]
  __bf16* Qb    = Wpb + (size_t)C_DIM * C_DIM;           // [16][2048][64]
  __bf16* Kb    = Qb + (size_t)NH * T_SEQ * HD;          // [4][2048][64]
  __bf16* Vt    = Kb + (size_t)NKV * T_SEQ * HD;         // [4][64][2048]
  __bf16* Yb    = Vt + (size_t)NKV * HD * T_SEQ;         // [2048][1024]
  float2* ropeT = (float2*)(Yb + (size_t)T_SEQ * C_DIM); // [2048][32]
  unsigned* bar = (unsigned*)((char*)d_ws + (22u << 20)); // 22MB offset, past layout

  hipMemsetAsync(bar, 0, 8, stream);  // workspace is poison-filled between iterations
  fused_kernel<<<dim3(NBLK), dim3(256), 0, stream>>>(
      x, Wq, Wkv, Wproj, out, xb, Wqkvb, Wpb, Qb, Kb, Vt, Yb, ropeT, bar);
}

// Round 11
// 107.850 us; speedup vs baseline: 4.7541x; 4.7541x over previous
//
#include <hip/hip_runtime.h>

#define T_SEQ 2048
#define C_DIM 1024
#define NH    16
#define NKV   4
#define HD    64
#define WIN   512

typedef __bf16 bf16x8 __attribute__((ext_vector_type(8)));
typedef __bf16 bf16x4 __attribute__((ext_vector_type(4)));
typedef float f32x4 __attribute__((ext_vector_type(4)));

#define MFMA16(a, b, c) __builtin_amdgcn_mfma_f32_16x16x32_bf16(a, b, c, 0, 0, 0)

// async global->LDS, 16B per lane, dest = wave-uniform base + lane*16
#define GLD16(g, s)                                                          \
  __builtin_amdgcn_global_load_lds(                                          \
      (const __attribute__((address_space(1))) void*)(g),                    \
      (__attribute__((address_space(3))) void*)(s), 16, 0, 0)

// ---------------- prep: fused f32->bf16 casts + RoPE table (R7, proven) ----------------
__global__ __launch_bounds__(256) void prep_kernel(const float* __restrict__ x,
                                                   const float* __restrict__ Wq,
                                                   const float* __restrict__ Wkv,
                                                   const float* __restrict__ Wp,
                                                   __bf16* __restrict__ xb,
                                                   __bf16* __restrict__ Wqkvb,
                                                   __bf16* __restrict__ Wpb,
                                                   float2* __restrict__ ropeT) {
  int b = blockIdx.x;
  if (b >= 4608) {
    int idx = (b - 4608) * 256 + threadIdx.x;  // < 65536
    int t = idx >> 5, i = idx & 31;
    float theta = exp2f(-(float)i * (13.287712379549449f / 32.0f));
    float s, c;
    sincosf((float)t * theta, &s, &c);
    ropeT[idx] = make_float2(c, s);
    return;
  }
  const float* src;
  __bf16* dst;
  int off;
  if (b < 2048)      { src = x;   dst = xb;                off = b; }
  else if (b < 3072) { src = Wq;  dst = Wqkvb;             off = b - 2048; }
  else if (b < 3584) { src = Wkv; dst = Wqkvb + (1 << 20); off = b - 3072; }
  else               { src = Wp;  dst = Wpb;               off = b - 3584; }
  int i = off * 1024 + threadIdx.x * 4;
  float4 v = *(const float4*)(src + i);
  bf16x4 o;
  o[0] = (__bf16)v.x; o[1] = (__bf16)v.y; o[2] = (__bf16)v.z; o[3] = (__bf16)v.w;
  *(bf16x4*)(dst + i) = o;
}

// ---------------- GEMM core v2: 64x64 tile, BK=64, QUAD-SPLIT waves ----------------
// R17: R4 core was 10 ds_read_b128 per 8 MFMA per wave (every wave read ALL 64
// B-rows); block total 40 reads / 32 MFMA -> LDS-read-bound (b128 ~12cyc/CU, m134).
// New: 2x2 wave grid, wave (wm,wn) owns the 32x32 quadrant [wm*32..][wn*32..]:
// per iter 4 A-frags + 4 B-frags for 8 MFMA -> block 32 reads / 32 MFMA (-20% LDS).
// Accumulation order per output element unchanged -> bit-identical numerics.
// Staging identical to R4 (gld_lds + source-side XOR swizzle, m173).
__device__ __forceinline__ void gemm_core64(const __bf16* __restrict__ A,
                                            const __bf16* __restrict__ B,
                                            int K,
                                            __bf16* AsB, __bf16* BsB,
                                            f32x4 (&acc)[2][2]) {
  const int tid = threadIdx.x;
  const int w = tid >> 6, l = tid & 63;
  const int quad = l >> 4, r16 = l & 15;
  const int wm = w >> 1, wn = w & 1;
  // staging: wave w fills rows [w*16, w*16+16) of A and B tiles (unchanged)
  const int srow = w * 16 + (l >> 3);
  const size_t soff = (size_t)srow * K + (size_t)(((l & 7) ^ (l >> 3)) * 8);
  const __bf16* gA = A + soff;
  const __bf16* gB = B + soff;
  __bf16* const lA = AsB + w * 1024;
  __bf16* const lB = BsB + w * 1024;
  const size_t rstep = (size_t)8 * K;
  // fragment read offsets: A rows wm*32+mt*16+r16, B rows wn*32+nt*16+r16
  int rA[2][2], rB[2][2];  // [mt|nt][ks] -- static-indexed only
#pragma unroll
  for (int mt = 0; mt < 2; ++mt)
#pragma unroll
    for (int ks = 0; ks < 2; ++ks) {
      int rowA = wm * 32 + mt * 16 + r16;
      rA[mt][ks] = rowA * 64 + (((ks * 4 + quad) ^ (rowA & 7)) * 8);
      int rowB = wn * 32 + mt * 16 + r16;
      rB[mt][ks] = rowB * 64 + (((ks * 4 + quad) ^ (rowB & 7)) * 8);
    }
  const int nIter = K >> 6;
  GLD16(gA, lA);
  GLD16(gA + rstep, lA + 512);
  GLD16(gB, lB);
  GLD16(gB + rstep, lB + 512);
  __syncthreads();
  int cur = 0;
  for (int it = 0; it < nIter; ++it) {
    if (it + 1 < nIter) {  // async-stage next K-slab into the other buffer
      const __bf16* ga = gA + ((it + 1) << 6);
      const __bf16* gb = gB + ((it + 1) << 6);
      __bf16* la = lA + ((cur ^ 1) << 12);
      __bf16* lb = lB + ((cur ^ 1) << 12);
      GLD16(ga, la);
      GLD16(ga + rstep, la + 512);
      GLD16(gb, lb);
      GLD16(gb + rstep, lb + 512);
    }
    const __bf16* Asc = AsB + (cur << 12);
    const __bf16* Bsc = BsB + (cur << 12);
#pragma unroll
    for (int ks = 0; ks < 2; ++ks) {
      bf16x8 fa0 = *(const bf16x8*)(Asc + rA[0][ks]);
      bf16x8 fa1 = *(const bf16x8*)(Asc + rA[1][ks]);
      bf16x8 fb0 = *(const bf16x8*)(Bsc + rB[0][ks]);
      bf16x8 fb1 = *(const bf16x8*)(Bsc + rB[1][ks]);
      acc[0][0] = MFMA16(fa0, fb0, acc[0][0]);
      acc[0][1] = MFMA16(fa0, fb1, acc[0][1]);
      acc[1][0] = MFMA16(fa1, fb0, acc[1][0]);
      acc[1][1] = MFMA16(fa1, fb1, acc[1][1]);
    }
    if (it + 1 < nIter) {
      __syncthreads();  // drains vmcnt(0): next slab resident; old buffer free
      cur ^= 1;
    }
  }
  __syncthreads();  // staging buffers reusable by caller after this
}

// ---------------- QKV GEMM + fused norm+RoPE (Q,K) / V-transpose epilogue ----------
// Q/K: norm needs all 64 cols per row, now split across wn-waves -> dump acc to f32
// LDS [64][65] (pad kills conflicts; staging dead), barrier, then run the EXACT
// R4-proven epilogue math per wave-owned rows, sourcing values from LDS.
// V: direct quadrant-mapped write into the transpose buffer (no roundtrip).
// C/D layout per quadrant (m89): row = base + quad*4 + reg, col = base + r16.
__global__ __launch_bounds__(256) void gemm_qkv_kernel(const __bf16* __restrict__ xb,
                                                       const __bf16* __restrict__ Wqkvb,
                                                       const float2* __restrict__ ropeT,
                                                       __bf16* __restrict__ Qb,
                                                       __bf16* __restrict__ Kb,
                                                       __bf16* __restrict__ Vt) {
  __shared__ __align__(16) __bf16 smem[16384];  // As 2x4096 | Bs 2x4096 (32 KB)
  __bf16* AsB = smem;
  __bf16* BsB = smem + 8192;
  f32x4 acc[2][2] = {};
  const int m0 = blockIdx.y * 64, n0 = blockIdx.x * 64;
  gemm_core64(xb + (size_t)m0 * C_DIM, Wqkvb + (size_t)n0 * C_DIM, C_DIM, AsB, BsB, acc);
  const int tid = threadIdx.x;
  const int w = tid >> 6, l = tid & 63, quad = l >> 4, r16 = l & 15;
  const int wm = w >> 1, wn = w & 1;
  if (n0 < 1280) {  // Q or K: L2-norm + RoPE (via f32 LDS roundtrip)
    float* Rb = (float*)smem;  // [64][65] = 16.6 KB
#pragma unroll
    for (int mt = 0; mt < 2; ++mt)
#pragma unroll
      for (int nt = 0; nt < 2; ++nt)
#pragma unroll
        for (int r = 0; r < 4; ++r)
          Rb[(wm * 32 + mt * 16 + quad * 4 + r) * 65 + wn * 32 + nt * 16 + r16] =
              acc[mt][nt][r];
    __syncthreads();
    const bool isQ = n0 < 1024;
    const int head = isQ ? (n0 >> 6) : ((n0 - 1024) >> 6);
    __bf16* dstBase = (isQ ? Qb : Kb) + (size_t)head * T_SEQ * HD;
    const float osc = isQ ? 0.125f : 1.0f;  // fold 1/sqrt(d) into Q (2^-3 exact)
#pragma unroll
    for (int r = 0; r < 4; ++r) {
      const float* row = Rb + (w * 16 + quad * 4 + r) * 65;
      const float a0 = row[r16], a1 = row[16 + r16];
      const float a2 = row[32 + r16], a3 = row[48 + r16];
      float ss = a0 * a0 + a1 * a1 + a2 * a2 + a3 * a3;
#pragma unroll
      for (int m = 1; m < 16; m <<= 1) ss += __shfl_xor(ss, m, 64);
      const float inv = osc / (sqrtf(ss) + 1e-6f);
      const int t = m0 + w * 16 + quad * 4 + r;
      const float2 cs0 = ropeT[t * 32 + r16];
      const float2 cs1 = ropeT[t * 32 + 16 + r16];
      const float v0 = a0 * inv, v1 = a1 * inv;
      const float v2 = a2 * inv, v3 = a3 * inv;
      __bf16* dst = dstBase + (size_t)t * HD;
      dst[r16]      = (__bf16)(v0 * cs0.x - v2 * cs0.y);
      dst[16 + r16] = (__bf16)(v1 * cs1.x - v3 * cs1.y);
      dst[32 + r16] = (__bf16)(v2 * cs0.x + v0 * cs0.y);
      dst[48 + r16] = (__bf16)(v3 * cs1.x + v1 * cs1.y);
    }
  } else {  // V: transpose to Vt[kvh][d][t] via reused LDS, direct quadrant write
    const int kvh = (n0 - 1280) >> 6;
    __bf16* Vs = smem;  // [64 d][stride 136] = 17.4 KB
#pragma unroll
    for (int mt = 0; mt < 2; ++mt)
#pragma unroll
      for (int nt = 0; nt < 2; ++nt)
#pragma unroll
        for (int r = 0; r < 4; ++r)
          Vs[(wn * 32 + nt * 16 + r16) * 136 + wm * 32 + mt * 16 + quad * 4 + r] =
              (__bf16)acc[mt][nt][r];
    __syncthreads();
    const int d = tid >> 2, tc = (tid & 3) * 16;
    __bf16* dst = Vt + ((size_t)kvh * HD + d) * T_SEQ + m0 + tc;
    bf16x8 v0 = *(const bf16x8*)(Vs + d * 136 + tc);
    bf16x8 v1 = *(const bf16x8*)(Vs + d * 136 + tc + 8);
    *(bf16x8*)dst = v0;
    *(bf16x8*)(dst + 8) = v1;
  }
}

// ---------------- proj GEMM: grid (16, 32), direct quadrant f32 epilogue ----------------
__global__ __launch_bounds__(256) void gemm_proj_kernel(const __bf16* __restrict__ Yb,
                                                        const __bf16* __restrict__ Wpb,
                                                        float* __restrict__ C) {
  __shared__ __align__(16) __bf16 smem[16384];
  __bf16* AsB = smem;
  __bf16* BsB = smem + 8192;
  f32x4 acc[2][2] = {};
  const int m0 = blockIdx.y * 64, n0 = blockIdx.x * 64;
  gemm_core64(Yb + (size_t)m0 * C_DIM, Wpb + (size_t)n0 * C_DIM, C_DIM, AsB, BsB, acc);
  const int tid = threadIdx.x;
  const int w = tid >> 6, l = tid & 63, quad = l >> 4, r16 = l & 15;
  const int wm = w >> 1, wn = w & 1;
  const int mrow = m0 + wm * 32 + quad * 4;
  const int ncol = n0 + wn * 32 + r16;
#pragma unroll
  for (int mt = 0; mt < 2; ++mt)
#pragma unroll
    for (int r = 0; r < 4; ++r) {
      size_t rowoff = (size_t)(mrow + mt * 16 + r) * C_DIM;
      C[rowoff + ncol]      = acc[mt][0][r];
      C[rowoff + ncol + 16] = acc[mt][1][r];
    }
}

// ---------------- MFMA sliding-window attention, block-cooperative LDS-staged ----------
// R12 (proven, -31 us): block = 64 queries (4 waves x 16 rows); per 64-key chunk
// the block stages K+V once into LDS (gld_lds + source XOR), double-buffered;
// one __syncthreads per chunk drains vmcnt. Numerics: R7-proven epilogue math.
__global__ __launch_bounds__(256) void attn_mfma_kernel(const __bf16* __restrict__ Qb,
                                                        const __bf16* __restrict__ Kb,
                                                        const __bf16* __restrict__ Vt,
                                                        __bf16* __restrict__ Yb) {
  __shared__ __align__(16) __bf16 KVs[2][8192];   // per buf: K[64][64] | V[64][64]
  __shared__ __align__(16) __bf16 Pl[4][16][72];
  const int h = blockIdx.y, kvh = h >> 2;
  const int t0 = blockIdx.x * 64;
  const int tid = threadIdx.x;
  const int w = tid >> 6, l = tid & 63;
  const int quad = l >> 4, r16 = l & 15;
  const int rr = l >> 3;          // 0..7: staging row within 8-row group
  const int cc = (l & 7) ^ rr;    // swizzled source chunk
  const __bf16* qptr = Qb + ((size_t)h * T_SEQ + t0 + w * 16 + r16) * HD + quad * 8;
  bf16x8 aq0 = *(const bf16x8*)(qptr);
  bf16x8 aq1 = *(const bf16x8*)(qptr + 32);
  const int keyStart = max(0, t0 - (WIN - 1)) & ~63;
  const int nch = ((t0 + 64) - keyStart) >> 6;         // <= 9, block-uniform
  const __bf16* kbase = Kb + (size_t)kvh * T_SEQ * HD;
  const __bf16* vbase = Vt + (size_t)kvh * HD * T_SEQ;
  const int tq = t0 + w * 16 + quad * 4;  // + r
  f32x4 oacc[4] = {};
  float lsum[4] = {0.f, 0.f, 0.f, 0.f};

  {  // prologue: stage chunk 0 into buf 0
    __bf16* kd = &KVs[0][w * 1024];
    __bf16* vd = &KVs[0][4096 + w * 1024];
    const __bf16* kg = kbase + (size_t)(keyStart + w * 16 + rr) * HD + cc * 8;
    const __bf16* vg = vbase + (size_t)(w * 16 + rr) * T_SEQ + keyStart + cc * 8;
    GLD16(kg, kd); GLD16(kg + 8 * HD, kd + 512);
    GLD16(vg, vd); GLD16(vg + 8 * T_SEQ, vd + 512);
  }
  __syncthreads();
  int buf = 0;
  for (int it = 0; it < nch; ++it) {
    const int key0 = keyStart + (it << 6);
    if (it + 1 < nch) {  // async-stage next chunk into the other buffer
      const int kn = key0 + 64;
      __bf16* kd = &KVs[buf ^ 1][w * 1024];
      __bf16* vd = &KVs[buf ^ 1][4096 + w * 1024];
      const __bf16* kg = kbase + (size_t)(kn + w * 16 + rr) * HD + cc * 8;
      const __bf16* vg = vbase + (size_t)(w * 16 + rr) * T_SEQ + kn + cc * 8;
      GLD16(kg, kd); GLD16(kg + 8 * HD, kd + 512);
      GLD16(vg, vd); GLD16(vg + 8 * T_SEQ, vd + 512);
    }
    const __bf16* Ksc = &KVs[buf][0];
    const __bf16* Vsc = &KVs[buf][4096];
    f32x4 s[4] = {};
#pragma unroll
    for (int nt = 0; nt < 4; ++nt) {
      const int row = nt * 16 + r16;
      bf16x8 bk0 = *(const bf16x8*)(Ksc + row * 64 + ((quad ^ (row & 7)) * 8));
      bf16x8 bk1 = *(const bf16x8*)(Ksc + row * 64 + (((4 + quad) ^ (row & 7)) * 8));
      s[nt] = MFMA16(aq0, bk0, s[nt]);
      s[nt] = MFMA16(aq1, bk1, s[nt]);
    }
#pragma unroll
    for (int nt = 0; nt < 4; ++nt) {
      const int key = key0 + nt * 16 + r16;
#pragma unroll
      for (int r = 0; r < 4; ++r) {
        bool valid = (key <= tq + r) && (key > tq + r - WIN);
        float p = valid ? __expf(s[nt][r]) : 0.0f;
        lsum[r] += p;
        Pl[w][quad * 4 + r][nt * 16 + r16] = (__bf16)p;
      }
    }
    bf16x8 ap0 = *(const bf16x8*)(&Pl[w][r16][quad * 8]);
    bf16x8 ap1 = *(const bf16x8*)(&Pl[w][r16][32 + quad * 8]);
#pragma unroll
    for (int nt = 0; nt < 4; ++nt) {
      const int d = nt * 16 + r16;
      bf16x8 bv0 = *(const bf16x8*)(Vsc + d * 64 + ((quad ^ (d & 7)) * 8));
      bf16x8 bv1 = *(const bf16x8*)(Vsc + d * 64 + (((4 + quad) ^ (d & 7)) * 8));
      oacc[nt] = MFMA16(ap0, bv0, oacc[nt]);
      oacc[nt] = MFMA16(ap1, bv1, oacc[nt]);
    }
    __syncthreads();  // drains vmcnt: next chunk resident; old buffer free
    buf ^= 1;
  }
#pragma unroll
  for (int r = 0; r < 4; ++r) {
#pragma unroll
    for (int m = 1; m < 16; m <<= 1) lsum[r] += __shfl_xor(lsum[r], m, 64);
  }
#pragma unroll
  for (int r = 0; r < 4; ++r) {
    const float inv = 1.0f / lsum[r];
    const size_t row = (size_t)(tq + r);
#pragma unroll
    for (int nt = 0; nt < 4; ++nt)
      Yb[row * C_DIM + h * HD + nt * 16 + r16] = (__bf16)(oacc[nt][r] * inv);
  }
}

extern "C" void kernel_launch(void* const* d_in, const int* in_sizes, int n_in,
                              void* d_out, int out_size, void* d_ws, size_t ws_size,
                              hipStream_t stream) {
  const float* x     = (const float*)d_in[0];
  const float* Wq    = (const float*)d_in[1];
  const float* Wkv   = (const float*)d_in[2];
  const float* Wproj = (const float*)d_in[3];
  float* out = (float*)d_out;

  __bf16* xb    = (__bf16*)d_ws;                         // [2048][1024]
  __bf16* Wqkvb = xb + (size_t)T_SEQ * C_DIM;            // [1536][1024]
  __bf16* Wpb   = Wqkvb + (size_t)1536 * C_DIM;          // [1024][1024]
  __bf16* Qb    = Wpb + (size_t)C_DIM * C_DIM;           // [16][2048][64]
  __bf16* Kb    = Qb + (size_t)NH * T_SEQ * HD;          // [4][2048][64]
  __bf16* Vt    = Kb + (size_t)NKV * T_SEQ * HD;         // [4][64][2048]
  __bf16* Yb    = Vt + (size_t)NKV * HD * T_SEQ;         // [2048][1024]
  float2* ropeT = (float2*)(Yb + (size_t)T_SEQ * C_DIM); // [2048][32]

  prep_kernel<<<4864, 256, 0, stream>>>(x, Wq, Wkv, Wproj, xb, Wqkvb, Wpb, ropeT);
  gemm_qkv_kernel<<<dim3(24, 32), 256, 0, stream>>>(xb, Wqkvb, ropeT, Qb, Kb, Vt);
  attn_mfma_kernel<<<dim3(T_SEQ / 64, NH), 256, 0, stream>>>(Qb, Kb, Vt, Yb);
  gemm_proj_kernel<<<dim3(16, 32), 256, 0, stream>>>(Yb, Wpb, out);
}